// Round 11
// baseline (265.156 us; speedup 1.0000x reference)
//
#include <hip/hip_runtime.h>
#include <stdint.h>

// Problem constants
#define B_SZ 4
#define S_LEN 2048
#define NH 16
#define HD 64
#define DM 1024

typedef __bf16 bf16;
typedef __bf16 bf16x4 __attribute__((ext_vector_type(4)));
typedef __bf16 bf16x8 __attribute__((ext_vector_type(8)));
typedef float f32x4 __attribute__((ext_vector_type(4)));

#define MFMA16(a, b, c) __builtin_amdgcn_mfma_f32_16x16x32_bf16(a, b, c, 0, 0, 0)

__device__ __forceinline__ void gl2lds16(const void* g, void* l) {
  __builtin_amdgcn_global_load_lds(
      (__attribute__((address_space(1))) const void*)g,
      (__attribute__((address_space(3))) void*)l, 16, 0, 0);
}

// Barrier that orders this wave's LDS ops (lgkm) only — does NOT drain
// vmcnt, so global/DMA loads prefetched for the next tile stay in flight.
__device__ __forceinline__ void bar_lgkm() {
  asm volatile("s_waitcnt lgkmcnt(0)\n\ts_barrier" ::: "memory");
}

// load 8 consecutive f32 and round to bf16x8
__device__ __forceinline__ bf16x8 ldcvt(const float* p) {
  f32x4 u0 = *(const f32x4*)p;
  f32x4 u1 = *(const f32x4*)(p + 4);
  bf16x8 v;
#pragma unroll
  for (int j = 0; j < 4; j++) {
    v[j] = (bf16)u0[j];
    v[4 + j] = (bf16)u1[j];
  }
  return v;
}

// ---------------------------------------------------------------------------
// Kernel 0: f32 -> bf16 conversion of x-chunk and the 4 weight matrices.
// ---------------------------------------------------------------------------
__global__ void cvt_kernel(const float* __restrict__ x,
                           const float* __restrict__ wq,
                           const float* __restrict__ wk,
                           const float* __restrict__ wv,
                           const float* __restrict__ wo,
                           bf16* __restrict__ Xb, bf16* __restrict__ Wb,
                           long xN) {
  const long e = ((long)blockIdx.x * 256 + threadIdx.x) * 8;
  const float* src;
  bf16* dst;
  long off;
  if (e < xN) {
    src = x; dst = Xb; off = e;
  } else {
    const long w = e - xN;
    const int wi = (int)(w >> 20);  // 1M elems per weight
    src = (wi == 0) ? wq : (wi == 1) ? wk : (wi == 2) ? wv : wo;
    dst = Wb + ((size_t)wi << 20);
    off = w & ((1L << 20) - 1);
  }
  *(bf16x8*)(dst + off) = ldcvt(src + off);
}

// ---------------------------------------------------------------------------
// 128x128 GEMM core (R8, proven): DOUBLE-BUFFERED global_load_lds with
// counted vmcnt. Used by out_gemm only since R11 (qkv moved to the 256^2
// structure below). C[m,n] = sum_k A[m,k]*B[n,k]. As/Bs = [2][128*32] bf16.
// ---------------------------------------------------------------------------
__device__ __forceinline__ void gemm_core_bb(const bf16* __restrict__ Ag,
                                             const bf16* __restrict__ Bg,
                                             f32x4 acc[4][4], bf16* As,
                                             bf16* Bs) {
  const int tid = threadIdx.x;
  const int lane = tid & 63;
  const int wave = tid >> 6;
  const int wm = (wave >> 1) * 64;
  const int wn = (wave & 1) * 64;
  const int col = lane & 15;
  const int kq = (lane >> 4) * 8;
  const int r0 = tid >> 2;       // staging row (pass 0)
  const int c0 = (tid & 3) * 8;  // staging col
#pragma unroll
  for (int i = 0; i < 4; i++)
#pragma unroll
    for (int j = 0; j < 4; j++) acc[i][j] = (f32x4){0.f, 0.f, 0.f, 0.f};

  // Prologue: DMA k-tile 0 into buffer 0.
  gl2lds16(Ag + (size_t)r0 * 1024 + c0, As + tid * 8);
  gl2lds16(Ag + (size_t)(r0 + 64) * 1024 + c0, As + 2048 + tid * 8);
  gl2lds16(Bg + (size_t)r0 * 1024 + c0, Bs + tid * 8);
  gl2lds16(Bg + (size_t)(r0 + 64) * 1024 + c0, Bs + 2048 + tid * 8);

  for (int ki = 0; ki < 32; ki++) {
    bar_lgkm();  // all waves closed reads of buf^1 (iter ki-1); safe to fill
    if (ki + 1 < 32) {
      const int kn = (ki + 1) * 32;
      bf16* Ad = As + ((ki + 1) & 1) * 4096;
      bf16* Bd = Bs + ((ki + 1) & 1) * 4096;
      gl2lds16(Ag + (size_t)r0 * 1024 + kn + c0, Ad + tid * 8);
      gl2lds16(Ag + (size_t)(r0 + 64) * 1024 + kn + c0, Ad + 2048 + tid * 8);
      gl2lds16(Bg + (size_t)r0 * 1024 + kn + c0, Bd + tid * 8);
      gl2lds16(Bg + (size_t)(r0 + 64) * 1024 + kn + c0, Bd + 2048 + tid * 8);
      // tile ki's 4 DMAs landed; ki+1's 4 stay in flight across the barrier
      asm volatile("s_waitcnt vmcnt(4)" ::: "memory");
    } else {
      asm volatile("s_waitcnt vmcnt(0)" ::: "memory");
    }
    asm volatile("s_barrier" ::: "memory");  // tile ki visible to all waves

    const bf16* Ac = As + (ki & 1) * 4096;
    const bf16* Bc = Bs + (ki & 1) * 4096;
    bf16x8 af[4], bfr[4];
#pragma unroll
    for (int i = 0; i < 4; i++)
      af[i] = *(const bf16x8*)(Ac + (wm + i * 16 + col) * 32 + kq);
#pragma unroll
    for (int j = 0; j < 4; j++)
      bfr[j] = *(const bf16x8*)(Bc + (wn + j * 16 + col) * 32 + kq);
#pragma unroll
    for (int i = 0; i < 4; i++)
#pragma unroll
      for (int j = 0; j < 4; j++)
        acc[i][j] = MFMA16(af[i], bfr[j], acc[i][j]);
  }
}

// ---------------------------------------------------------------------------
// Kernel 1 (R11): QKV projection on the 256^2 / 8-wave / BK=64 structure,
// + fused V transpose + fused RoPE (R10's epilogue, i-range doubled).
// R10 measured: the 128^2 2-phase core sits at ~670 TF = the documented
// 2-phase ceiling (m230/m233: stage+vmcnt+barrier ~72% of critical path).
// This structure (guide ladder: 1563 TF @4k) fixes the three structural
// costs: (a) per-wave 128x64 output -> MFMA:ds_read = 64:24 = 2.67 (was
// 2.0); (b) 2 barriers per ~2500-cyc K-tile (was per ~620); (c) deep
// counted-vmcnt prefetch (vmcnt(8): next K-tile's 8 DMAs in flight across
// both barriers) substitutes for occupancy at 1 block/CU (128KB LDS).
// Swizzle (both-sides involution, proven in attn R7): LDS rows linear
// (gl2lds dest = base + tid*16), global SOURCE 16B-col pre-swizzled
// c16 ^= (row&7), ds_read applies the same XOR. b128 reads spread 8
// lanes/16B-slot = structural minimum (conflict-free).
// Waves: wid>>2 = m-half (128 rows), wid&3 = n-quarter (64 cols).
// Grid (bcnt*8, 12): wsel = by>>2 (Q/K/V), n0 = (by&3)*256.
// ---------------------------------------------------------------------------
__global__ __launch_bounds__(512, 2) void qkv_gemm(
    const bf16* __restrict__ x, const bf16* __restrict__ Wb,
    const int* __restrict__ tp, bf16* __restrict__ Q, bf16* __restrict__ K,
    bf16* __restrict__ Vt) {
  __shared__ __align__(16) bf16 As[2][256 * 64];  // 2 x 32 KB
  __shared__ __align__(16) bf16 Bs[2][256 * 64];  // 2 x 32 KB -> 128 KB total

  const int tid = threadIdx.x;
  const int lane = tid & 63;
  const int wid = tid >> 6;  // 0..7
  const int wr = wid >> 2;   // m-half: rows wr*128..+127
  const int wc = wid & 3;    // n-quarter: cols wc*64..+63
  const int col = lane & 15, quad = lane >> 4;
  const int bx = blockIdx.x;
  const int by = blockIdx.y;
  const int wsel = by >> 2;
  const int n0 = (by & 3) * 256;
  const bf16* Ag = x + (size_t)bx * 256 * 1024;
  const bf16* Bg = Wb + ((size_t)wsel << 20) + (size_t)n0 * 1024;

  // staging ids: one gl2lds = 512 thr x 16B = 8 KB = 64 rows of 128 B
  const int sr = tid >> 3;              // row within 64-row chunk
  const int sc = (tid & 7) ^ (sr & 7);  // pre-swizzled source 16B column

  f32x4 acc[8][4];
#pragma unroll
  for (int i = 0; i < 8; i++)
#pragma unroll
    for (int j = 0; j < 4; j++) acc[i][j] = (f32x4){0.f, 0.f, 0.f, 0.f};

  auto stage = [&](int b, int kt) {
    const int k0 = kt * 64;
#pragma unroll
    for (int ch = 0; ch < 4; ch++) {
      gl2lds16(Ag + (size_t)(ch * 64 + sr) * 1024 + k0 + sc * 8,
               &As[b][ch * 4096 + tid * 8]);
      gl2lds16(Bg + (size_t)(ch * 64 + sr) * 1024 + k0 + sc * 8,
               &Bs[b][ch * 4096 + tid * 8]);
    }
  };

  stage(0, 0);  // prologue: K-tile 0 -> buffer 0
  for (int kt = 0; kt < 16; kt++) {
    bar_lgkm();  // close previous iteration's ds_reads of buf (kt+1)&1
    if (kt + 1 < 16) {
      stage((kt + 1) & 1, kt + 1);
      // kt's 8 DMAs landed; kt+1's 8 stay in flight across the barrier
      asm volatile("s_waitcnt vmcnt(8)" ::: "memory");
    } else {
      asm volatile("s_waitcnt vmcnt(0)" ::: "memory");
    }
    asm volatile("s_barrier" ::: "memory");  // tile kt visible to all waves

    const bf16* Ac = As[kt & 1];
    const bf16* Bc = Bs[kt & 1];
#pragma unroll
    for (int ks = 0; ks < 2; ks++) {  // two k32 halves of BK=64
      bf16x8 bfr[4];
#pragma unroll
      for (int j = 0; j < 4; j++) {
        const int row = wc * 64 + j * 16 + col;  // row&7 == col&7
        bfr[j] = *(const bf16x8*)(Bc + row * 64 +
                                  (((ks * 4 + quad) ^ (col & 7)) << 3));
      }
#pragma unroll
      for (int i = 0; i < 8; i++) {
        const int row = wr * 128 + i * 16 + col;
        bf16x8 af = *(const bf16x8*)(Ac + row * 64 +
                                     (((ks * 4 + quad) ^ (col & 7)) << 3));
#pragma unroll
        for (int j = 0; j < 4; j++) acc[i][j] = MFMA16(af, bfr[j], acc[i][j]);
      }
    }
  }

  // Epilogue: fused RoPE for Q/K (native __sinf/__cosf + lane pairing,
  // proven R10) or V transpose. h = (by&3)*4 + wc; d = j*16+col.
  const int h = (by & 3) * 4 + wc;
  if (wsel < 2) {
    bf16* dst = wsel ? K : Q;
    const float qs = wsel ? 1.0f : 0.18033688011112042f;  // 0.125*log2(e)
    const int codd = col & 1;
    float freqs[4];
#pragma unroll
    for (int j = 0; j < 4; j++)
      freqs[j] = __builtin_exp2f(-(float)(j * 8 + (col >> 1)) *
                                 0.41524101186091903f);
#pragma unroll
    for (int i = 0; i < 8; i++) {
      const int m0 = bx * 256 + wr * 128 + i * 16 + quad * 4;
#pragma unroll
      for (int r = 0; r < 4; r++) {
        const int mm = m0 + r;  // pass-local row
        const int bl = mm >> 11, s = mm & 2047;
        const float pf = (float)tp[s];
#pragma unroll
        for (int j = 0; j < 4; j++) {
          const int d = j * 16 + col;
          const float own = acc[i][j][r];
          const float oth = __shfl_xor(own, 1);  // RoPE partner (d^1)
          const float ang = pf * freqs[j];
          const float mine = codd ? __cosf(ang) : __sinf(ang);
          const float thr = __shfl_xor(mine, 1);
          const float sn = codd ? thr : mine;
          const float cn = codd ? mine : thr;
          const float res =
              codd ? (oth * sn + own * cn) : (own * cn - oth * sn);
          dst[((((size_t)bl * NH + h) * S_LEN + s) << 6) + d] =
              (bf16)(res * qs);
        }
      }
    }
  } else {  // V: write transposed [bh][d][s], 4 consecutive s per store
#pragma unroll
    for (int i = 0; i < 8; i++) {
      const int m0 = bx * 256 + wr * 128 + i * 16 + quad * 4;
      const int bl = m0 >> 11, s = m0 & 2047;
#pragma unroll
      for (int j = 0; j < 4; j++) {
        const int d = j * 16 + col;
        bf16x4 pk;
#pragma unroll
        for (int r = 0; r < 4; r++) pk[r] = (bf16)acc[i][j][r];
        *(bf16x4*)(Vt + (((size_t)(bl * NH + h) * 64 + d) << 11) + s) = pk;
      }
    }
  }
}

// ---------------------------------------------------------------------------
// Kernel 4: causal flash attention (R7 structure, unchanged): DMA-staged
// K/V (global_load_lds) with XOR-swizzled SOURCE + double buffer + counted
// vmcnt. Swizzle (rule #21): LDS linear [64][64]; global source 16B-column
// pre-swizzled c16 ^= (row&7); fragment reads apply the same involution.
// Pipeline (T4): bar_lgkm -> issue 4 gl2lds for kt+1 -> vmcnt(4) ->
// s_barrier -> compute. LDS 51200B -> 3 blocks/CU; grid (64,16) refills.
// No max-tracking softmax (scale folded into Q via RoPE); l reduced across
// quads once at epilogue.
// ---------------------------------------------------------------------------
#define PP 72  // Ps row pitch (144B stride -> 2-way bank conflict, free)
__global__ __launch_bounds__(256, 2) void attn_kernel(
    const bf16* __restrict__ Q, const bf16* __restrict__ K,
    const bf16* __restrict__ Vt, bf16* __restrict__ O) {
  __shared__ __align__(16) bf16 Kb[2][64 * 64];   // 2 x 8192 B
  __shared__ __align__(16) bf16 Vb[2][64 * 64];   // 2 x 8192 B
  __shared__ __align__(16) bf16 Ps[4 * 32 * PP];  // 18432 B

  const int tid = threadIdx.x, lane = tid & 63, wave = tid >> 6;  // wave 0..3
  const int col = lane & 15, quad = lane >> 4, kq = quad * 8;
  const int bh = blockIdx.x;
  const int yb = blockIdx.y;
  const int qt = (yb < 8) ? (15 - yb) : (yb - 8);  // balanced co-res sets
  const int bl = bh >> 4, h = bh & 15;
  const bf16* Kg = K + (size_t)bh * S_LEN * 64;
  const bf16* Vg = Vt + (size_t)bh * 64 * S_LEN;
  bf16* Pw = Ps + wave * 32 * PP;
  const int wq_abs = qt * 128 + wave * 32;  // this wave's first q row
  const int qmax = wq_abs + 31;

  // DMA staging ids: 256 thr x 16B = 4KB = 32 rows of 128B per call.
  const int r_ = tid >> 3;                // dest row (0..31)
  const int cs_ = (tid & 7) ^ (r_ & 7);   // swizzled source 16B-column
  const int kx = col & 7;                 // read-side involution key

  // Q fragments: 2 m-tiles x (K=64 -> 2 chained), straight from global
  const bf16* Qg = Q + ((size_t)bh * S_LEN + wq_abs) * 64;
  bf16x8 qf[2][2];
#pragma unroll
  for (int mi = 0; mi < 2; mi++)
#pragma unroll
    for (int kc = 0; kc < 2; kc++)
      qf[mi][kc] =
          *(const bf16x8*)(Qg + (mi * 16 + col) * 64 + kc * 32 + kq);

  f32x4 oacc[2][4];
  float lst[2] = {0.f, 0.f};
#pragma unroll
  for (int mi = 0; mi < 2; mi++)
#pragma unroll
    for (int nd = 0; nd < 4; nd++) oacc[mi][nd] = (f32x4){0.f, 0.f, 0.f, 0.f};

  const int ntiles = 2 * qt + 2;  // 64-key tiles covering [0, (qt+1)*128)

  // Prologue: DMA tile 0 into buffer 0 (K rows r_, r_+32; V d-rows same).
  gl2lds16(Kg + (size_t)r_ * 64 + cs_ * 8, Kb[0] + tid * 8);
  gl2lds16(Kg + (size_t)(r_ + 32) * 64 + cs_ * 8, Kb[0] + 2048 + tid * 8);
  gl2lds16(Vg + (size_t)r_ * S_LEN + cs_ * 8, Vb[0] + tid * 8);
  gl2lds16(Vg + (size_t)(r_ + 32) * S_LEN + cs_ * 8, Vb[0] + 2048 + tid * 8);

  for (int kt = 0; kt < ntiles; kt++) {
    bar_lgkm();  // all waves done reading buf^1 (tile kt-1); safe to refill
    if (kt + 1 < ntiles) {
      bf16* kd = Kb[(kt + 1) & 1];
      bf16* vd = Vb[(kt + 1) & 1];
      const bf16* Kn = Kg + (size_t)(kt + 1) * 64 * 64;
      const bf16* Vn = Vg + (kt + 1) * 64;
      gl2lds16(Kn + (size_t)r_ * 64 + cs_ * 8, kd + tid * 8);
      gl2lds16(Kn + (size_t)(r_ + 32) * 64 + cs_ * 8, kd + 2048 + tid * 8);
      gl2lds16(Vn + (size_t)r_ * S_LEN + cs_ * 8, vd + tid * 8);
      gl2lds16(Vn + (size_t)(r_ + 32) * S_LEN + cs_ * 8, vd + 2048 + tid * 8);
      // tile kt's 4 DMAs landed; kt+1's 4 stay in flight across the barrier
      asm volatile("s_waitcnt vmcnt(4)" ::: "memory");
    } else {
      asm volatile("s_waitcnt vmcnt(0)" ::: "memory");
    }
    asm volatile("s_barrier" ::: "memory");  // all waves' DMAs for kt visible

    const int kb = kt * 64;
    if (kb > qmax) continue;  // all keys masked for this wave (staging only)
    const bf16* Kc = Kb[kt & 1];
    const bf16* Vc = Vb[kt & 1];

    // S^T[key][q] for 64 keys x 32 q (swizzled K reads)
    f32x4 sa[2][4];
#pragma unroll
    for (int ni = 0; ni < 4; ni++) {
      const int krow = ni * 16 + col;
      bf16x8 kf0 = *(const bf16x8*)(Kc + krow * 64 + ((quad ^ kx) << 3));
      bf16x8 kf1 =
          *(const bf16x8*)(Kc + krow * 64 + (((quad + 4) ^ kx) << 3));
#pragma unroll
      for (int mi = 0; mi < 2; mi++) {
        f32x4 s = {0.f, 0.f, 0.f, 0.f};
        s = MFMA16(kf0, qf[mi][0], s);
        s = MFMA16(kf1, qf[mi][1], s);
        sa[mi][ni] = s;  // reg r: key = kb+ni*16+quad*4+r, q = wq_abs+mi*16+col
      }
    }
    if (kb + 63 > wq_abs) {  // diagonal band: elementwise causal mask
      const int base = kb - wq_abs + quad * 4;
#pragma unroll
      for (int mi = 0; mi < 2; mi++)
#pragma unroll
        for (int ni = 0; ni < 4; ni++)
#pragma unroll
          for (int r = 0; r < 4; r++)
            if (base + ni * 16 + r > mi * 16 + col) sa[mi][ni][r] = -1e30f;
    }
    // P = exp2(s'), lane-local partial l (cross-quad reduce deferred)
#pragma unroll
    for (int mi = 0; mi < 2; mi++) {
      float rs = 0.f;
#pragma unroll
      for (int ni = 0; ni < 4; ni++)
#pragma unroll
        for (int r = 0; r < 4; r++) {
          float pv = __builtin_exp2f(sa[mi][ni][r]);
          sa[mi][ni][r] = pv;
          rs += pv;
        }
      lst[mi] += rs;
    }
    // P -> per-wave LDS (C-layout -> A-layout), conflict-free b64 writes
#pragma unroll
    for (int mi = 0; mi < 2; mi++)
#pragma unroll
      for (int ni = 0; ni < 4; ni++) {
        bf16x4 pk;
#pragma unroll
        for (int r = 0; r < 4; r++) pk[r] = (bf16)sa[mi][ni][r];
        *(bf16x4*)(Pw + (mi * 16 + col) * PP + ni * 16 + quad * 4) = pk;
      }
    // O += P @ V for this 64-key tile (2 MFMA k-steps, swizzled V reads)
#pragma unroll
    for (int kcl = 0; kcl < 2; kcl++) {
      bf16x8 pf[2];
#pragma unroll
      for (int mi = 0; mi < 2; mi++)
        pf[mi] = *(const bf16x8*)(Pw + (mi * 16 + col) * PP + kcl * 32 + kq);
#pragma unroll
      for (int nd = 0; nd < 4; nd++) {
        const int vrow = nd * 16 + col;
        bf16x8 vf = *(const bf16x8*)(Vc + vrow * 64 +
                                     (((kcl * 4 + quad) ^ kx) << 3));
#pragma unroll
        for (int mi = 0; mi < 2; mi++)
          oacc[mi][nd] = MFMA16(pf[mi], vf, oacc[mi][nd]);
      }
    }
  }

  // Epilogue: reduce l across quads once, O = oacc / l
#pragma unroll
  for (int mi = 0; mi < 2; mi++) {
    float rs = lst[mi];
    rs += __shfl_xor(rs, 16);
    rs += __shfl_xor(rs, 32);
    const float il = 1.0f / rs;
    float linv[4];
#pragma unroll
    for (int r = 0; r < 4; r++) linv[r] = __shfl(il, quad * 4 + r);
    const int srow0 = wq_abs + mi * 16 + quad * 4;
#pragma unroll
    for (int nd = 0; nd < 4; nd++)
#pragma unroll
      for (int r = 0; r < 4; r++)
        O[(size_t)(bl * S_LEN + srow0 + r) * DM + h * 64 + nd * 16 + col] =
            (bf16)(oacc[mi][nd][r] * linv[r]);
  }
}

// ---------------------------------------------------------------------------
// Kernel 5: output projection (A bf16, W bf16, out f32). grid (bcnt*16, 8).
// ---------------------------------------------------------------------------
__global__ __launch_bounds__(256, 4) void out_gemm(const bf16* __restrict__ A,
                                                   const bf16* __restrict__ W,
                                                   float* __restrict__ out) {
  __shared__ __align__(16) bf16 As[2 * 128 * 32];
  __shared__ __align__(16) bf16 Bs[2 * 128 * 32];
  f32x4 acc[4][4];
  gemm_core_bb(A + (size_t)blockIdx.x * 128 * 1024,
               W + (size_t)blockIdx.y * 128 * 1024, acc, As, Bs);
  const int lane = threadIdx.x & 63;
  const int wave = threadIdx.x >> 6;
  const int wm = (wave >> 1) * 64, wn = (wave & 1) * 64;
  const int col = lane & 15, quad = lane >> 4;
#pragma unroll
  for (int i = 0; i < 4; i++) {
    const int m0 = blockIdx.x * 128 + wm + i * 16 + quad * 4;
#pragma unroll
    for (int j = 0; j < 4; j++) {
      const int n = blockIdx.y * 128 + wn + j * 16 + col;
#pragma unroll
      for (int r = 0; r < 4; r++)
        out[(size_t)(m0 + r) * DM + n] = acc[i][j][r];
    }
  }
}

// ---------------------------------------------------------------------------
extern "C" void kernel_launch(void* const* d_in, const int* in_sizes, int n_in,
                              void* d_out, int out_size, void* d_ws,
                              size_t ws_size, hipStream_t stream) {
  const float* x = (const float*)d_in[0];
  const int* tp = (const int*)d_in[1];
  const float* wq = (const float*)d_in[2];
  const float* wk = (const float*)d_in[3];
  const float* wv = (const float*)d_in[4];
  const float* wo = (const float*)d_in[5];
  float* out = (float*)d_out;
  bf16* wsb = (bf16*)d_ws;

  const size_t TENb = (size_t)NH * S_LEN * HD;  // 2M elems = per-batch tensor
  const size_t WSZ = 4ull * DM * DM;            // 4M elems (4 bf16 weights)
  int bcnt = 1;
  if (ws_size >= (4 * 4 * TENb + WSZ) * sizeof(bf16)) bcnt = 4;       // 72 MB
  else if (ws_size >= (4 * 2 * TENb + WSZ) * sizeof(bf16)) bcnt = 2;  // 40 MB

  const size_t REG = (size_t)bcnt * TENb;
  bf16* Xb = wsb;             // [bcnt,S,DM] bf16 x; later aliased by Ow
  bf16* Qw = wsb + REG;       // [bcnt,H,S,D]
  bf16* Kw = wsb + 2 * REG;   // [bcnt,H,S,D]
  bf16* Vtw = wsb + 3 * REG;  // [bcnt,H,D,S]
  bf16* Wb = wsb + 4 * REG;   // [4,DM,DM] bf16 weights (wq|wk|wv|wo)
  bf16* Ow = Xb;              // [bcnt,S,H*D], x dead after qkv_gemm

  for (int b0 = 0; b0 < B_SZ; b0 += bcnt) {
    const float* xb = x + (size_t)b0 * S_LEN * DM;
    float* outb = out + (size_t)b0 * S_LEN * DM;
    const long cvtN = (long)(REG + WSZ);  // elems, divisible by 2048
    hipLaunchKernelGGL(cvt_kernel, dim3((unsigned)(cvtN / 2048)), dim3(256), 0,
                       stream, xb, wq, wk, wv, wo, Xb, Wb, (long)REG);
    hipLaunchKernelGGL(qkv_gemm, dim3(bcnt * 8, 12), dim3(512), 0, stream,
                       Xb, Wb, tp, Qw, Kw, Vtw);
    hipLaunchKernelGGL(attn_kernel, dim3(bcnt * 16, 16), dim3(256), 0, stream,
                       Qw, Kw, Vtw, Ow);
    hipLaunchKernelGGL(out_gemm, dim3(bcnt * 16, 8), dim3(256), 0, stream,
                       Ow, Wb + 3ull * DM * DM, outb);
  }
}

// Round 13
// 250.998 us; speedup vs baseline: 1.0564x; 1.0564x over previous
//
#include <hip/hip_runtime.h>
#include <stdint.h>

// Problem constants
#define B_SZ 4
#define S_LEN 2048
#define NH 16
#define HD 64
#define DM 1024

typedef __bf16 bf16;
typedef __bf16 bf16x4 __attribute__((ext_vector_type(4)));
typedef __bf16 bf16x8 __attribute__((ext_vector_type(8)));
typedef float f32x4 __attribute__((ext_vector_type(4)));

#define MFMA16(a, b, c) __builtin_amdgcn_mfma_f32_16x16x32_bf16(a, b, c, 0, 0, 0)

__device__ __forceinline__ void gl2lds16(const void* g, void* l) {
  __builtin_amdgcn_global_load_lds(
      (__attribute__((address_space(1))) const void*)g,
      (__attribute__((address_space(3))) void*)l, 16, 0, 0);
}

// Barrier that orders this wave's LDS ops (lgkm) only — does NOT drain
// vmcnt, so global/DMA loads prefetched for the next tile stay in flight.
__device__ __forceinline__ void bar_lgkm() {
  asm volatile("s_waitcnt lgkmcnt(0)\n\ts_barrier" ::: "memory");
}

// load 8 consecutive f32 and round to bf16x8
__device__ __forceinline__ bf16x8 ldcvt(const float* p) {
  f32x4 u0 = *(const f32x4*)p;
  f32x4 u1 = *(const f32x4*)(p + 4);
  bf16x8 v;
#pragma unroll
  for (int j = 0; j < 4; j++) {
    v[j] = (bf16)u0[j];
    v[4 + j] = (bf16)u1[j];
  }
  return v;
}

// ---------------------------------------------------------------------------
// Kernel 0: f32 -> bf16 conversion of x-chunk and the 4 weight matrices.
// ---------------------------------------------------------------------------
__global__ void cvt_kernel(const float* __restrict__ x,
                           const float* __restrict__ wq,
                           const float* __restrict__ wk,
                           const float* __restrict__ wv,
                           const float* __restrict__ wo,
                           bf16* __restrict__ Xb, bf16* __restrict__ Wb,
                           long xN) {
  const long e = ((long)blockIdx.x * 256 + threadIdx.x) * 8;
  const float* src;
  bf16* dst;
  long off;
  if (e < xN) {
    src = x; dst = Xb; off = e;
  } else {
    const long w = e - xN;
    const int wi = (int)(w >> 20);  // 1M elems per weight
    src = (wi == 0) ? wq : (wi == 1) ? wk : (wi == 2) ? wv : wo;
    dst = Wb + ((size_t)wi << 20);
    off = w & ((1L << 20) - 1);
  }
  *(bf16x8*)(dst + off) = ldcvt(src + off);
}

// ---------------------------------------------------------------------------
// 128x128 GEMM core (R8, proven best: qkv 77us): DOUBLE-BUFFERED
// global_load_lds with counted vmcnt. Per iter: bar_lgkm (close prev reads,
// NO vmcnt drain) -> issue 4 DMAs for tile k+1 into buf^1 -> s_waitcnt
// vmcnt(4) (tile k landed, k+1 in flight) -> s_barrier -> compute buf k.
// R11 post-mortem: the 256^2/BK=64 2-phase variant REGRESSED (110us): 1
// block/CU (128KB LDS; acc=128 regs caps 2 waves/SIMD regardless), grid
// tail (384 blocks / 256 slots = 1.5 rounds), and 256^2 only pays with the
// full 8-phase interleave (regime gate). Reverted to this core.
// C[m,n] = sum_k A[m,k]*B[n,k]. As/Bs = [2][128*32] bf16.
// ---------------------------------------------------------------------------
__device__ __forceinline__ void gemm_core_bb(const bf16* __restrict__ Ag,
                                             const bf16* __restrict__ Bg,
                                             f32x4 acc[4][4], bf16* As,
                                             bf16* Bs) {
  const int tid = threadIdx.x;
  const int lane = tid & 63;
  const int wave = tid >> 6;
  const int wm = (wave >> 1) * 64;
  const int wn = (wave & 1) * 64;
  const int col = lane & 15;
  const int kq = (lane >> 4) * 8;
  const int r0 = tid >> 2;       // staging row (pass 0)
  const int c0 = (tid & 3) * 8;  // staging col
#pragma unroll
  for (int i = 0; i < 4; i++)
#pragma unroll
    for (int j = 0; j < 4; j++) acc[i][j] = (f32x4){0.f, 0.f, 0.f, 0.f};

  // Prologue: DMA k-tile 0 into buffer 0.
  gl2lds16(Ag + (size_t)r0 * 1024 + c0, As + tid * 8);
  gl2lds16(Ag + (size_t)(r0 + 64) * 1024 + c0, As + 2048 + tid * 8);
  gl2lds16(Bg + (size_t)r0 * 1024 + c0, Bs + tid * 8);
  gl2lds16(Bg + (size_t)(r0 + 64) * 1024 + c0, Bs + 2048 + tid * 8);

  for (int ki = 0; ki < 32; ki++) {
    bar_lgkm();  // all waves closed reads of buf^1 (iter ki-1); safe to fill
    if (ki + 1 < 32) {
      const int kn = (ki + 1) * 32;
      bf16* Ad = As + ((ki + 1) & 1) * 4096;
      bf16* Bd = Bs + ((ki + 1) & 1) * 4096;
      gl2lds16(Ag + (size_t)r0 * 1024 + kn + c0, Ad + tid * 8);
      gl2lds16(Ag + (size_t)(r0 + 64) * 1024 + kn + c0, Ad + 2048 + tid * 8);
      gl2lds16(Bg + (size_t)r0 * 1024 + kn + c0, Bd + tid * 8);
      gl2lds16(Bg + (size_t)(r0 + 64) * 1024 + kn + c0, Bd + 2048 + tid * 8);
      // tile ki's 4 DMAs landed; ki+1's 4 stay in flight across the barrier
      asm volatile("s_waitcnt vmcnt(4)" ::: "memory");
    } else {
      asm volatile("s_waitcnt vmcnt(0)" ::: "memory");
    }
    asm volatile("s_barrier" ::: "memory");  // tile ki visible to all waves

    const bf16* Ac = As + (ki & 1) * 4096;
    const bf16* Bc = Bs + (ki & 1) * 4096;
    bf16x8 af[4], bfr[4];
#pragma unroll
    for (int i = 0; i < 4; i++)
      af[i] = *(const bf16x8*)(Ac + (wm + i * 16 + col) * 32 + kq);
#pragma unroll
    for (int j = 0; j < 4; j++)
      bfr[j] = *(const bf16x8*)(Bc + (wn + j * 16 + col) * 32 + kq);
#pragma unroll
    for (int i = 0; i < 4; i++)
#pragma unroll
      for (int j = 0; j < 4; j++)
        acc[i][j] = MFMA16(af[i], bfr[j], acc[i][j]);
  }
}

// ---------------------------------------------------------------------------
// Kernel 1: fused QKV projection + fused V transpose + FUSED ROPE
// (R10 config, proven 77.4us / total 255.1us).
// RoPE in-register before the bf16 store via native __sinf/__cosf (R9's
// sincosf was a non-inlined OCML call -> 165MB scratch; fixed R10) with
// lane pairing: adjacent lanes (col even/odd) need the same angle -> even
// lane computes sin, odd cos, one __shfl_xor exchanges. Partner value via
// __shfl_xor(acc,1). t = j*8+(col>>1); angle = tp[s]*exp2(-t*log2(1e4)/32).
// Q scaled by 0.125*log2(e) (folds softmax scale + exp2 base into QK^T).
// grid (bcnt*16, 24): wsel = by>>3 -> Q/K/V; n0 = (by&7)*128.
// ---------------------------------------------------------------------------
__global__ __launch_bounds__(256, 4) void qkv_gemm(
    const bf16* __restrict__ x, const bf16* __restrict__ Wb,
    const int* __restrict__ tp, bf16* __restrict__ Q, bf16* __restrict__ K,
    bf16* __restrict__ Vt) {
  __shared__ __align__(16) bf16 As[2 * 128 * 32];
  __shared__ __align__(16) bf16 Bs[2 * 128 * 32];
  const int bx = blockIdx.x;
  const int by = blockIdx.y;
  const int wsel = by >> 3;
  const int n0 = (by & 7) * 128;

  f32x4 acc[4][4];
  gemm_core_bb(x + (size_t)bx * 128 * 1024,
               Wb + ((size_t)wsel << 20) + (size_t)n0 * 1024, acc, As, Bs);

  const int lane = threadIdx.x & 63;
  const int wave = threadIdx.x >> 6;
  const int wm = (wave >> 1) * 64, wn = (wave & 1) * 64;
  const int col = lane & 15, quad = lane >> 4;

  if (wsel < 2) {
    bf16* dst = wsel ? K : Q;
    const float qs = wsel ? 1.0f : 0.18033688011112042f;  // 0.125*log2(e)
    const int codd = col & 1;
    // freq per j: t = j*8 + (col>>1)
    float freqs[4];
#pragma unroll
    for (int j = 0; j < 4; j++)
      freqs[j] = __builtin_exp2f(-(float)(j * 8 + (col >> 1)) *
                                 0.41524101186091903f);
#pragma unroll
    for (int i = 0; i < 4; i++) {
      const int m0 = bx * 128 + wm + i * 16 + quad * 4;
#pragma unroll
      for (int r = 0; r < 4; r++) {
        const int mm = m0 + r;  // pass-local row
        const int bl = mm >> 11, s = mm & 2047;
        const float pf = (float)tp[s];
#pragma unroll
        for (int j = 0; j < 4; j++) {
          const int n = n0 + wn + j * 16 + col;  // [0,1024)
          const int h = n >> 6, d = n & 63;
          const float own = acc[i][j][r];
          const float oth = __shfl_xor(own, 1);  // RoPE partner (d^1)
          const float ang = pf * freqs[j];
          // even lane computes sin, odd computes cos; exchange via shfl
          const float mine = codd ? __cosf(ang) : __sinf(ang);
          const float thr = __shfl_xor(mine, 1);
          const float sn = codd ? thr : mine;
          const float cn = codd ? mine : thr;
          // even d: xe*cos - xo*sin ; odd d: xe*sin + xo*cos
          const float res = codd ? (oth * sn + own * cn) : (own * cn - oth * sn);
          dst[((((size_t)bl * NH + h) * S_LEN + s) << 6) + d] =
              (bf16)(res * qs);
        }
      }
    }
  } else {  // V: write transposed [bh][d][s], 4 consecutive s per store
#pragma unroll
    for (int i = 0; i < 4; i++) {
      const int m0 = bx * 128 + wm + i * 16 + quad * 4;
      const int bl = m0 >> 11, s = m0 & 2047;
#pragma unroll
      for (int j = 0; j < 4; j++) {
        const int n = n0 + wn + j * 16 + col;
        const int h = n >> 6, d = n & 63;
        bf16x4 pk;
#pragma unroll
        for (int r = 0; r < 4; r++) pk[r] = (bf16)acc[i][j][r];
        *(bf16x4*)(Vt + (((size_t)(bl * NH + h) * 64 + d) << 11) + s) = pk;
      }
    }
  }
}

// ---------------------------------------------------------------------------
// Kernel 4: causal flash attention (R7 structure + R12 setprio): DMA-staged
// K/V (global_load_lds) with XOR-swizzled SOURCE + double buffer + counted
// vmcnt. Swizzle (rule #21): LDS linear [64][64]; global source 16B-column
// pre-swizzled c16 ^= (row&7); fragment reads apply the same involution.
// Pipeline (T4): bar_lgkm -> issue 4 gl2lds for kt+1 -> vmcnt(4) ->
// s_barrier -> compute. LDS 51200B -> 3 blocks/CU; grid (64,16) refills.
// R12: s_setprio(1) wraps the QK^T and PV MFMA clusters (T5). Regime: ~3
// INDEPENDENT blocks/CU at different kt phases -> on a SIMD, one block's
// wave is in its long VALU softmax stretch while another enters MFMA; the
// priority hint lets MFMA waves win issue slots (m191 attn regime, +4-7%;
// distinct from m190's lockstep-GEMM null).
// No max-tracking softmax (scale folded into Q via RoPE); l reduced across
// quads once at epilogue.
// ---------------------------------------------------------------------------
#define PP 72  // Ps row pitch (144B stride -> 2-way bank conflict, free)
__global__ __launch_bounds__(256, 2) void attn_kernel(
    const bf16* __restrict__ Q, const bf16* __restrict__ K,
    const bf16* __restrict__ Vt, bf16* __restrict__ O) {
  __shared__ __align__(16) bf16 Kb[2][64 * 64];   // 2 x 8192 B
  __shared__ __align__(16) bf16 Vb[2][64 * 64];   // 2 x 8192 B
  __shared__ __align__(16) bf16 Ps[4 * 32 * PP];  // 18432 B

  const int tid = threadIdx.x, lane = tid & 63, wave = tid >> 6;  // wave 0..3
  const int col = lane & 15, quad = lane >> 4, kq = quad * 8;
  const int bh = blockIdx.x;
  const int yb = blockIdx.y;
  const int qt = (yb < 8) ? (15 - yb) : (yb - 8);  // balanced co-res sets
  const int bl = bh >> 4, h = bh & 15;
  const bf16* Kg = K + (size_t)bh * S_LEN * 64;
  const bf16* Vg = Vt + (size_t)bh * 64 * S_LEN;
  bf16* Pw = Ps + wave * 32 * PP;
  const int wq_abs = qt * 128 + wave * 32;  // this wave's first q row
  const int qmax = wq_abs + 31;

  // DMA staging ids: 256 thr x 16B = 4KB = 32 rows of 128B per call.
  const int r_ = tid >> 3;                // dest row (0..31)
  const int cs_ = (tid & 7) ^ (r_ & 7);   // swizzled source 16B-column
  const int kx = col & 7;                 // read-side involution key

  // Q fragments: 2 m-tiles x (K=64 -> 2 chained), straight from global
  const bf16* Qg = Q + ((size_t)bh * S_LEN + wq_abs) * 64;
  bf16x8 qf[2][2];
#pragma unroll
  for (int mi = 0; mi < 2; mi++)
#pragma unroll
    for (int kc = 0; kc < 2; kc++)
      qf[mi][kc] =
          *(const bf16x8*)(Qg + (mi * 16 + col) * 64 + kc * 32 + kq);

  f32x4 oacc[2][4];
  float lst[2] = {0.f, 0.f};
#pragma unroll
  for (int mi = 0; mi < 2; mi++)
#pragma unroll
    for (int nd = 0; nd < 4; nd++) oacc[mi][nd] = (f32x4){0.f, 0.f, 0.f, 0.f};

  const int ntiles = 2 * qt + 2;  // 64-key tiles covering [0, (qt+1)*128)

  // Prologue: DMA tile 0 into buffer 0 (K rows r_, r_+32; V d-rows same).
  gl2lds16(Kg + (size_t)r_ * 64 + cs_ * 8, Kb[0] + tid * 8);
  gl2lds16(Kg + (size_t)(r_ + 32) * 64 + cs_ * 8, Kb[0] + 2048 + tid * 8);
  gl2lds16(Vg + (size_t)r_ * S_LEN + cs_ * 8, Vb[0] + tid * 8);
  gl2lds16(Vg + (size_t)(r_ + 32) * S_LEN + cs_ * 8, Vb[0] + 2048 + tid * 8);

  for (int kt = 0; kt < ntiles; kt++) {
    bar_lgkm();  // all waves done reading buf^1 (tile kt-1); safe to refill
    if (kt + 1 < ntiles) {
      bf16* kd = Kb[(kt + 1) & 1];
      bf16* vd = Vb[(kt + 1) & 1];
      const bf16* Kn = Kg + (size_t)(kt + 1) * 64 * 64;
      const bf16* Vn = Vg + (kt + 1) * 64;
      gl2lds16(Kn + (size_t)r_ * 64 + cs_ * 8, kd + tid * 8);
      gl2lds16(Kn + (size_t)(r_ + 32) * 64 + cs_ * 8, kd + 2048 + tid * 8);
      gl2lds16(Vn + (size_t)r_ * S_LEN + cs_ * 8, vd + tid * 8);
      gl2lds16(Vn + (size_t)(r_ + 32) * S_LEN + cs_ * 8, vd + 2048 + tid * 8);
      // tile kt's 4 DMAs landed; kt+1's 4 stay in flight across the barrier
      asm volatile("s_waitcnt vmcnt(4)" ::: "memory");
    } else {
      asm volatile("s_waitcnt vmcnt(0)" ::: "memory");
    }
    asm volatile("s_barrier" ::: "memory");  // all waves' DMAs for kt visible

    const int kb = kt * 64;
    if (kb > qmax) continue;  // all keys masked for this wave (staging only)
    const bf16* Kc = Kb[kt & 1];
    const bf16* Vc = Vb[kt & 1];

    // S^T[key][q] for 64 keys x 32 q (swizzled K reads) — T5 setprio
    f32x4 sa[2][4];
    __builtin_amdgcn_s_setprio(1);
#pragma unroll
    for (int ni = 0; ni < 4; ni++) {
      const int krow = ni * 16 + col;
      bf16x8 kf0 = *(const bf16x8*)(Kc + krow * 64 + ((quad ^ kx) << 3));
      bf16x8 kf1 =
          *(const bf16x8*)(Kc + krow * 64 + (((quad + 4) ^ kx) << 3));
#pragma unroll
      for (int mi = 0; mi < 2; mi++) {
        f32x4 s = {0.f, 0.f, 0.f, 0.f};
        s = MFMA16(kf0, qf[mi][0], s);
        s = MFMA16(kf1, qf[mi][1], s);
        sa[mi][ni] = s;  // reg r: key = kb+ni*16+quad*4+r, q = wq_abs+mi*16+col
      }
    }
    __builtin_amdgcn_s_setprio(0);
    if (kb + 63 > wq_abs) {  // diagonal band: elementwise causal mask
      const int base = kb - wq_abs + quad * 4;
#pragma unroll
      for (int mi = 0; mi < 2; mi++)
#pragma unroll
        for (int ni = 0; ni < 4; ni++)
#pragma unroll
          for (int r = 0; r < 4; r++)
            if (base + ni * 16 + r > mi * 16 + col) sa[mi][ni][r] = -1e30f;
    }
    // P = exp2(s'), lane-local partial l (cross-quad reduce deferred)
#pragma unroll
    for (int mi = 0; mi < 2; mi++) {
      float rs = 0.f;
#pragma unroll
      for (int ni = 0; ni < 4; ni++)
#pragma unroll
        for (int r = 0; r < 4; r++) {
          float pv = __builtin_exp2f(sa[mi][ni][r]);
          sa[mi][ni][r] = pv;
          rs += pv;
        }
      lst[mi] += rs;
    }
    // P -> per-wave LDS (C-layout -> A-layout), conflict-free b64 writes
#pragma unroll
    for (int mi = 0; mi < 2; mi++)
#pragma unroll
      for (int ni = 0; ni < 4; ni++) {
        bf16x4 pk;
#pragma unroll
        for (int r = 0; r < 4; r++) pk[r] = (bf16)sa[mi][ni][r];
        *(bf16x4*)(Pw + (mi * 16 + col) * PP + ni * 16 + quad * 4) = pk;
      }
    // O += P @ V for this 64-key tile (2 MFMA k-steps, swizzled V reads)
    __builtin_amdgcn_s_setprio(1);
#pragma unroll
    for (int kcl = 0; kcl < 2; kcl++) {
      bf16x8 pf[2];
#pragma unroll
      for (int mi = 0; mi < 2; mi++)
        pf[mi] = *(const bf16x8*)(Pw + (mi * 16 + col) * PP + kcl * 32 + kq);
#pragma unroll
      for (int nd = 0; nd < 4; nd++) {
        const int vrow = nd * 16 + col;
        bf16x8 vf = *(const bf16x8*)(Vc + vrow * 64 +
                                     (((kcl * 4 + quad) ^ kx) << 3));
#pragma unroll
        for (int mi = 0; mi < 2; mi++)
          oacc[mi][nd] = MFMA16(pf[mi], vf, oacc[mi][nd]);
      }
    }
    __builtin_amdgcn_s_setprio(0);
  }

  // Epilogue: reduce l across quads once, O = oacc / l
#pragma unroll
  for (int mi = 0; mi < 2; mi++) {
    float rs = lst[mi];
    rs += __shfl_xor(rs, 16);
    rs += __shfl_xor(rs, 32);
    const float il = 1.0f / rs;
    float linv[4];
#pragma unroll
    for (int r = 0; r < 4; r++) linv[r] = __shfl(il, quad * 4 + r);
    const int srow0 = wq_abs + mi * 16 + quad * 4;
#pragma unroll
    for (int nd = 0; nd < 4; nd++)
#pragma unroll
      for (int r = 0; r < 4; r++)
        O[(size_t)(bl * S_LEN + srow0 + r) * DM + h * 64 + nd * 16 + col] =
            (bf16)(oacc[mi][nd][r] * linv[r]);
  }
}

// ---------------------------------------------------------------------------
// Kernel 5: output projection (A bf16, W bf16, out f32). grid (bcnt*16, 8).
// ---------------------------------------------------------------------------
__global__ __launch_bounds__(256, 4) void out_gemm(const bf16* __restrict__ A,
                                                   const bf16* __restrict__ W,
                                                   float* __restrict__ out) {
  __shared__ __align__(16) bf16 As[2 * 128 * 32];
  __shared__ __align__(16) bf16 Bs[2 * 128 * 32];
  f32x4 acc[4][4];
  gemm_core_bb(A + (size_t)blockIdx.x * 128 * 1024,
               W + (size_t)blockIdx.y * 128 * 1024, acc, As, Bs);
  const int lane = threadIdx.x & 63;
  const int wave = threadIdx.x >> 6;
  const int wm = (wave >> 1) * 64, wn = (wave & 1) * 64;
  const int col = lane & 15, quad = lane >> 4;
#pragma unroll
  for (int i = 0; i < 4; i++) {
    const int m0 = blockIdx.x * 128 + wm + i * 16 + quad * 4;
#pragma unroll
    for (int j = 0; j < 4; j++) {
      const int n = blockIdx.y * 128 + wn + j * 16 + col;
#pragma unroll
      for (int r = 0; r < 4; r++)
        out[(size_t)(m0 + r) * DM + n] = acc[i][j][r];
    }
  }
}

// ---------------------------------------------------------------------------
extern "C" void kernel_launch(void* const* d_in, const int* in_sizes, int n_in,
                              void* d_out, int out_size, void* d_ws,
                              size_t ws_size, hipStream_t stream) {
  const float* x = (const float*)d_in[0];
  const int* tp = (const int*)d_in[1];
  const float* wq = (const float*)d_in[2];
  const float* wk = (const float*)d_in[3];
  const float* wv = (const float*)d_in[4];
  const float* wo = (const float*)d_in[5];
  float* out = (float*)d_out;
  bf16* wsb = (bf16*)d_ws;

  const size_t TENb = (size_t)NH * S_LEN * HD;  // 2M elems = per-batch tensor
  const size_t WSZ = 4ull * DM * DM;            // 4M elems (4 bf16 weights)
  int bcnt = 1;
  if (ws_size >= (4 * 4 * TENb + WSZ) * sizeof(bf16)) bcnt = 4;       // 72 MB
  else if (ws_size >= (4 * 2 * TENb + WSZ) * sizeof(bf16)) bcnt = 2;  // 40 MB

  const size_t REG = (size_t)bcnt * TENb;
  bf16* Xb = wsb;             // [bcnt,S,DM] bf16 x; later aliased by Ow
  bf16* Qw = wsb + REG;       // [bcnt,H,S,D]
  bf16* Kw = wsb + 2 * REG;   // [bcnt,H,S,D]
  bf16* Vtw = wsb + 3 * REG;  // [bcnt,H,D,S]
  bf16* Wb = wsb + 4 * REG;   // [4,DM,DM] bf16 weights (wq|wk|wv|wo)
  bf16* Ow = Xb;              // [bcnt,S,H*D], x dead after qkv_gemm

  for (int b0 = 0; b0 < B_SZ; b0 += bcnt) {
    const float* xb = x + (size_t)b0 * S_LEN * DM;
    float* outb = out + (size_t)b0 * S_LEN * DM;
    const long cvtN = (long)(REG + WSZ);  // elems, divisible by 2048
    hipLaunchKernelGGL(cvt_kernel, dim3((unsigned)(cvtN / 2048)), dim3(256), 0,
                       stream, xb, wq, wk, wv, wo, Xb, Wb, (long)REG);
    hipLaunchKernelGGL(qkv_gemm, dim3(bcnt * 16, 24), dim3(256), 0, stream,
                       Xb, Wb, tp, Qw, Kw, Vtw);
    hipLaunchKernelGGL(attn_kernel, dim3(bcnt * 16, 16), dim3(256), 0, stream,
                       Qw, Kw, Vtw, Ow);
    hipLaunchKernelGGL(out_gemm, dim3(bcnt * 16, 8), dim3(256), 0, stream,
                       Ow, Wb + 3ull * DM * DM, outb);
  }
}